// Round 18
// baseline (135.101 us; speedup 1.0000x reference)
//
#include <hip/hip_runtime.h>
#include <stdint.h>

typedef unsigned short u16;
typedef unsigned int u32;
typedef u32 u32x4 __attribute__((ext_vector_type(4)));
typedef __bf16 bf16x8 __attribute__((ext_vector_type(8)));
typedef __bf16 bf16x4 __attribute__((ext_vector_type(4)));
typedef float f32x4 __attribute__((ext_vector_type(4)));

// fp32 -> bf16 round-to-nearest-even
__device__ __forceinline__ u16 f2bf(float f) {
  u32 u = __float_as_uint(f);
  u = (u + 0x7fffu + ((u >> 16) & 1u)) >> 16;
  return (u16)u;
}

// async global->LDS, 16B per lane; lds base must be wave-uniform (HW adds lane*16)
__device__ __forceinline__ void gload16(const void* g, void* l) {
  __builtin_amdgcn_global_load_lds(
      (const __attribute__((address_space(1))) void*)g,
      (__attribute__((address_space(3))) void*)l, 16, 0, 0);
}

// ---------------- prep: W [1024][1024] fp32 -> W^T bf16 (W only now) -------
__global__ __launch_bounds__(256) void prep_k(
    const float* __restrict__ w0, const float* __restrict__ w1,
    const float* __restrict__ w2, const float* __restrict__ w3,
    u16* __restrict__ wt) {
  __shared__ float tile[64][65];
  const int t = blockIdx.x;
  const int z = t >> 8;            // 0..3 -> Wq,Wk,Wv,Wo
  const int rem = t & 255;
  const int x0 = (rem & 15) * 64, y0 = (rem >> 4) * 64;
  const float* W = (z == 0) ? w0 : (z == 1) ? w1 : (z == 2) ? w2 : w3;
  u16* Wt = wt + (size_t)z * 1048576u;
  const int tx = threadIdx.x & 63, ty = threadIdx.x >> 6;  // 64 x 4
#pragma unroll
  for (int j = 0; j < 16; ++j)
    tile[ty + j * 4][tx] = W[(size_t)(y0 + ty + j * 4) * 1024 + x0 + tx];
  __syncthreads();
#pragma unroll
  for (int j = 0; j < 16; ++j)
    Wt[(size_t)(x0 + ty + j * 4) * 1024 + y0 + tx] = f2bf(tile[tx][ty + j * 4]);
}

// ---------------- merged projection GEMM (Q, K, V^T), fp32-X fused cvt -----
// z=0: Qb = (q @ Wq + bq) * qsc      (A = q fp32 via gload16, B = Wq^T bf16)
// z=1: Kb =  k @ Wk + bk             (A = k fp32, B = Wk^T bf16)
// z=2: VtG = (Wv^T . v^T) + bv(row)  (A = Wv^T bf16, B = v fp32)
// The fp32 operand is staged RAW into LDS with global_load_lds (async path
// preserved — R12's reg-staging regression avoided); fp32->bf16 happens in
// the LDS->register fragment read (2x ds_read_b128 + cvt per fragment).
// fp32 tile swizzle: 16B-chunk key c ^ ((row&7)<<1); read-side ^((row&7)<<5).
__global__ __launch_bounds__(256, 3) void gemm_proj(
    const float* __restrict__ qin, const float* __restrict__ kin,
    const float* __restrict__ vin, const u16* __restrict__ Wt,
    const float* __restrict__ bqp, const float* __restrict__ bkp,
    const float* __restrict__ bvp,
    u16* __restrict__ Qb, u16* __restrict__ Kb, u16* __restrict__ VtG,
    float qsc) {
  const int z = blockIdx.z;
  const float* Xf;          // fp32 operand
  const u16* Wb;            // bf16 operand
  const float* bias;
  u16* C;
  int N, bm, bn;
  float osc = 1.f;
  bool rowb = false;
  if (z < 2) {
    Xf = z ? kin : qin;
    Wb = Wt + (size_t)z * 1048576u;
    bias = z ? bkp : bqp;
    C = z ? Kb : Qb;
    N = 1024;
    bm = blockIdx.x * 128;
    bn = blockIdx.y * 128;
    if (z == 0) osc = qsc;
  } else {
    Wb = Wt + 2u * 1048576u;
    Xf = vin;
    bias = bvp;
    C = VtG;
    N = 4096;
    bm = blockIdx.y * 128;
    bn = blockIdx.x * 128;
    rowb = true;
  }

  // 48KB: fp32 tile (128x64 f32 = 32KB) at 0, bf16 tile (16KB) at 32768
  __shared__ __align__(16) char lds[49152];
  char* ldsF = lds;
  char* ldsH = lds + 32768;

  const int tid = threadIdx.x;
  const int lane = tid & 63, wv = tid >> 6;
  const int wr = wv >> 1, wc = wv & 1;
  const int l15 = lane & 15, l4 = lane >> 4;

  const f32x4 zero4 = {0.f, 0.f, 0.f, 0.f};
  f32x4 acc[4][4];
#pragma unroll
  for (int i = 0; i < 4; ++i)
#pragma unroll
    for (int j = 0; j < 4; ++j) acc[i][j] = zero4;

  for (int kt = 0; kt < 16; ++kt) {
    __syncthreads();
    {
      // stage fp32 operand: 2048 16B-chunks (4 floats each)
      const int fbase = (z < 2) ? bm : bn;
#pragma unroll
      for (int g = 0; g < 8; ++g) {
        int p = g * 256 + tid;
        int row = p >> 4;
        int c = p & 15;
        int ss = c ^ ((row & 7) << 1);
        gload16(Xf + (size_t)(fbase + row) * 1024 + kt * 64 + ss * 4,
                ldsF + (g * 256 + wv * 64) * 16);
      }
      // stage bf16 operand: 1024 16B-chunks (8 bf16 each)
      const int hbase = (z < 2) ? bn : bm;
#pragma unroll
      for (int g = 0; g < 4; ++g) {
        int p = g * 256 + tid;
        int row = p >> 3;
        int ss = (p & 7) ^ (row & 7);
        gload16(Wb + (size_t)(hbase + row) * 1024 + kt * 64 + ss * 8,
                ldsH + (g * 256 + wv * 64) * 16);
      }
    }
    __syncthreads();

    bf16x8 af[4][2], bfr[4][2];
#pragma unroll
    for (int mf = 0; mf < 4; ++mf) {
      int row = wr * 64 + mf * 16 + l15;
#pragma unroll
      for (int ks = 0; ks < 2; ++ks) {
        if (z < 2) {  // A from fp32 tile
          int sw = (row & 7) << 5;
          const char* rp = ldsF + row * 256;
          int off = (ks * 128 + l4 * 32) ^ sw;
          f32x4 a = *(const f32x4*)(rp + off);
          f32x4 b = *(const f32x4*)(rp + off + 16);
          bf16x4 ca = __builtin_convertvector(a, bf16x4);
          bf16x4 cb = __builtin_convertvector(b, bf16x4);
          af[mf][ks] = __builtin_shufflevector(ca, cb, 0, 1, 2, 3, 4, 5, 6, 7);
        } else {      // A from bf16 tile
          int byt = row * 128 + ((ks * 64 + l4 * 16) ^ ((row & 7) << 4));
          af[mf][ks] = *(const bf16x8*)(ldsH + byt);
        }
      }
    }
#pragma unroll
    for (int nf = 0; nf < 4; ++nf) {
      int row = wc * 64 + nf * 16 + l15;
#pragma unroll
      for (int ks = 0; ks < 2; ++ks) {
        if (z < 2) {  // B from bf16 tile
          int byt = row * 128 + ((ks * 64 + l4 * 16) ^ ((row & 7) << 4));
          bfr[nf][ks] = *(const bf16x8*)(ldsH + byt);
        } else {      // B from fp32 tile
          int sw = (row & 7) << 5;
          const char* rp = ldsF + row * 256;
          int off = (ks * 128 + l4 * 32) ^ sw;
          f32x4 a = *(const f32x4*)(rp + off);
          f32x4 b = *(const f32x4*)(rp + off + 16);
          bf16x4 ca = __builtin_convertvector(a, bf16x4);
          bf16x4 cb = __builtin_convertvector(b, bf16x4);
          bfr[nf][ks] = __builtin_shufflevector(ca, cb, 0, 1, 2, 3, 4, 5, 6, 7);
        }
      }
    }
    __builtin_amdgcn_s_setprio(1);
#pragma unroll
    for (int mf = 0; mf < 4; ++mf)
#pragma unroll
      for (int nf = 0; nf < 4; ++nf) {
        acc[mf][nf] = __builtin_amdgcn_mfma_f32_16x16x32_bf16(
            af[mf][0], bfr[nf][0], acc[mf][nf], 0, 0, 0);
        acc[mf][nf] = __builtin_amdgcn_mfma_f32_16x16x32_bf16(
            af[mf][1], bfr[nf][1], acc[mf][nf], 0, 0, 0);
      }
    __builtin_amdgcn_s_setprio(0);
  }

  float bcol[4];
  if (!rowb) {
#pragma unroll
    for (int nf = 0; nf < 4; ++nf)
      bcol[nf] = bias[bn + wc * 64 + nf * 16 + l15];
  }
#pragma unroll
  for (int mf = 0; mf < 4; ++mf) {
#pragma unroll
    for (int i = 0; i < 4; ++i) {
      int r = bm + wr * 64 + mf * 16 + l4 * 4 + i;
      float br = rowb ? bias[r] : 0.f;
#pragma unroll
      for (int nf = 0; nf < 4; ++nf) {
        int c = bn + wc * 64 + nf * 16 + l15;
        float val = (acc[mf][nf][i] + (rowb ? br : bcol[nf])) * osc;
        C[(size_t)r * N + c] = f2bf(val);
      }
    }
  }
}

// ---------------- final GEMM: out = ctx @ Wo^T' + bo (fp32) ----------------
__global__ __launch_bounds__(256, 3) void gemm_out(
    const u16* __restrict__ A, const u16* __restrict__ Bt,
    const float* __restrict__ bias, float* __restrict__ C) {
  __shared__ __align__(16) u16 ldsA[128 * 64];
  __shared__ __align__(16) u16 ldsB[128 * 64];

  const int tid = threadIdx.x;
  const int lane = tid & 63, wv = tid >> 6;
  const int wr = wv >> 1, wc = wv & 1;
  const int l15 = lane & 15, l4 = lane >> 4;
  const int bm = blockIdx.x * 128, bn = blockIdx.y * 128;

  const f32x4 zero4 = {0.f, 0.f, 0.f, 0.f};
  f32x4 acc[4][4];
#pragma unroll
  for (int i = 0; i < 4; ++i)
#pragma unroll
    for (int j = 0; j < 4; ++j) acc[i][j] = zero4;

  for (int kt = 0; kt < 16; ++kt) {
    __syncthreads();
#pragma unroll
    for (int g = 0; g < 4; ++g) {
      int p = g * 256 + tid;
      int row = p >> 3;
      int ss = (p & 7) ^ (row & 7);
      gload16(A + (size_t)(bm + row) * 1024 + kt * 64 + ss * 8,
              (char*)ldsA + (g * 256 + wv * 64) * 16);
    }
#pragma unroll
    for (int g = 0; g < 4; ++g) {
      int p = g * 256 + tid;
      int row = p >> 3;
      int ss = (p & 7) ^ (row & 7);
      gload16(Bt + (size_t)(bn + row) * 1024 + kt * 64 + ss * 8,
              (char*)ldsB + (g * 256 + wv * 64) * 16);
    }
    __syncthreads();

    bf16x8 af[4][2], bfr[4][2];
#pragma unroll
    for (int mf = 0; mf < 4; ++mf) {
      int row = wr * 64 + mf * 16 + l15;
#pragma unroll
      for (int ks = 0; ks < 2; ++ks) {
        int byt = row * 128 + ((ks * 64 + l4 * 16) ^ ((row & 7) << 4));
        af[mf][ks] = *(const bf16x8*)((const char*)ldsA + byt);
      }
    }
#pragma unroll
    for (int nf = 0; nf < 4; ++nf) {
      int row = wc * 64 + nf * 16 + l15;
#pragma unroll
      for (int ks = 0; ks < 2; ++ks) {
        int byt = row * 128 + ((ks * 64 + l4 * 16) ^ ((row & 7) << 4));
        bfr[nf][ks] = *(const bf16x8*)((const char*)ldsB + byt);
      }
    }
#pragma unroll
    for (int mf = 0; mf < 4; ++mf)
#pragma unroll
      for (int nf = 0; nf < 4; ++nf) {
        acc[mf][nf] = __builtin_amdgcn_mfma_f32_16x16x32_bf16(
            af[mf][0], bfr[nf][0], acc[mf][nf], 0, 0, 0);
        acc[mf][nf] = __builtin_amdgcn_mfma_f32_16x16x32_bf16(
            af[mf][1], bfr[nf][1], acc[mf][nf], 0, 0, 0);
      }
  }

  float bcol[4];
#pragma unroll
  for (int nf = 0; nf < 4; ++nf)
    bcol[nf] = bias[bn + wc * 64 + nf * 16 + l15];
#pragma unroll
  for (int mf = 0; mf < 4; ++mf) {
#pragma unroll
    for (int i = 0; i < 4; ++i) {
      int r = bm + wr * 64 + mf * 16 + l4 * 4 + i;
#pragma unroll
      for (int nf = 0; nf < 4; ++nf) {
        int c = bn + wc * 64 + nf * 16 + l15;
        C[(size_t)r * 1024 + c] = acc[mf][nf][i] + bcol[nf];
      }
    }
  }
}

// ---------------- causal flash attention: lane-local P (R17, frozen) -------
__global__ __launch_bounds__(256, 4) void attn_k(
    const u16* __restrict__ Q, const u16* __restrict__ Kb,
    const u16* __restrict__ Vt, u16* __restrict__ ctx) {
  const int id = blockIdx.x + (blockIdx.y << 5);
  const int xcd = id & 7;
  const int kk = id >> 3;               // 0..127
  const int bh = xcd * 4 + (kk & 3);    // 4 bh columns per XCD
  const int qt = 31 - (kk >> 2);        // q-tile, longest first
  const int b = bh >> 4, h = bh & 15;
  const int tid = threadIdx.x;
  const int lane = tid & 63, wv = tid >> 6;
  const int l15 = lane & 15, l4 = lane >> 4;

  __shared__ __align__(16) u16 Kt[2][64 * 64];   // [kv][d], perm-key swizzled
  __shared__ __align__(16) u16 Vl[2][64 * 64];   // [d][kv], row&7 swizzled

  const u16* KB = Kb + (size_t)(b * 2048) * 1024 + h * 64;
  const u16* VB = Vt + (size_t)(h * 64) * 4096 + b * 2048;

  const u16* qp =
      Q + (size_t)(b * 2048 + qt * 64 + wv * 16 + l15) * 1024 + h * 64;
  bf16x8 qf0 = *(const bf16x8*)(qp + l4 * 8);
  bf16x8 qf1 = *(const bf16x8*)(qp + 32 + l4 * 8);

  const f32x4 zero4 = {0.f, 0.f, 0.f, 0.f};
  f32x4 oacc[4];  // [nt]: O[q=l4*4+i][d=nt*16+l15]
#pragma unroll
  for (int i = 0; i < 4; ++i) oacc[i] = zero4;
  f32x4 lacc = zero4;  // lacc[i] = sum_kv P[q=l4*4+i][kv] (MFMA-accumulated)

  const u32x4 onesw = {0x3F803F80u, 0x3F803F80u, 0x3F803F80u, 0x3F803F80u};
  const bf16x8 onesf = __builtin_bit_cast(bf16x8, onesw);

  auto issueKV = [&](int jt, int bufi) {
    const u16* kb = KB + (size_t)(jt * 64) * 1024;
#pragma unroll
    for (int g = 0; g < 2; ++g) {
      int p = g * 256 + tid;
      int row = p >> 3;
      int key = (row & 3) | (((row >> 3) & 1) << 2);
      int ss = (p & 7) ^ key;
      gload16(kb + (size_t)row * 1024 + ss * 8,
              (char*)(&Kt[bufi][0]) + (g * 256 + wv * 64) * 16);
    }
#pragma unroll
    for (int g = 0; g < 2; ++g) {
      int p = g * 256 + tid;
      int d = p >> 3;
      int ss = (p & 7) ^ (d & 7);
      gload16(VB + (size_t)d * 4096 + jt * 64 + ss * 8,
              (char*)(&Vl[bufi][0]) + (g * 256 + wv * 64) * 16);
    }
  };

  issueKV(0, 0);
  for (int j = 0; j <= qt; ++j) {
    const int cur = j & 1;
    __syncthreads();  // own-vmcnt drain -> tile j in LDS; frees other buffer
    if (j < qt) issueKV(j + 1, cur ^ 1);

    // S^T tiles with permuted K rows: tile nt reads row =
    // 32*(nt>>1) + 4*(nt&1) + 8*(l15>>2) + (l15&3)
    f32x4 p4[4];
    __builtin_amdgcn_s_setprio(1);
#pragma unroll
    for (int nt = 0; nt < 4; ++nt) {
      int row = ((nt & 2) << 4) + ((nt & 1) << 2) + 8 * (l15 >> 2) + (l15 & 3);
      int key = (row & 3) | (((row >> 3) & 1) << 2);
      int sw = key << 4;
      const char* kr = (const char*)&Kt[cur][0] + row * 128;
      bf16x8 k0 = *(const bf16x8*)(kr + ((l4 * 16) ^ sw));
      bf16x8 k1 = *(const bf16x8*)(kr + ((64 + l4 * 16) ^ sw));
      f32x4 s = zero4;
      s = __builtin_amdgcn_mfma_f32_16x16x32_bf16(k0, qf0, s, 0, 0, 0);
      s = __builtin_amdgcn_mfma_f32_16x16x32_bf16(k1, qf1, s, 0, 0, 0);
      p4[nt] = s;
    }
    __builtin_amdgcn_s_setprio(0);

    if (j == qt) {  // causal mask: kv_local = 32*(nt>>1)+4*(nt&1)+8*l4+i
#pragma unroll
      for (int nt = 0; nt < 4; ++nt) {
        int kvb = ((nt & 2) << 4) + ((nt & 1) << 2) + 8 * l4;
#pragma unroll
        for (int i = 0; i < 4; ++i)
          if (kvb + i > wv * 16 + l15) p4[nt][i] = -1e30f;
      }
    }

    // p = exp2(S) (fixed reference; exp2(-1e30)=0 keeps masking exact)
#pragma unroll
    for (int nt = 0; nt < 4; ++nt)
#pragma unroll
      for (int i = 0; i < 4; ++i) p4[nt][i] = exp2f(p4[nt][i]);

    // PV A-frags directly from registers (k-order matches V's B-frag)
    bf16x4 c0 = __builtin_convertvector(p4[0], bf16x4);
    bf16x4 c1 = __builtin_convertvector(p4[1], bf16x4);
    bf16x4 c2 = __builtin_convertvector(p4[2], bf16x4);
    bf16x4 c3 = __builtin_convertvector(p4[3], bf16x4);
    bf16x8 pa0 = __builtin_shufflevector(c0, c1, 0, 1, 2, 3, 4, 5, 6, 7);
    bf16x8 pa1 = __builtin_shufflevector(c2, c3, 0, 1, 2, 3, 4, 5, 6, 7);

    // O += P V ; lsum += P . ones (on the matrix pipe)
    __builtin_amdgcn_s_setprio(1);
    lacc = __builtin_amdgcn_mfma_f32_16x16x32_bf16(pa0, onesf, lacc, 0, 0, 0);
    lacc = __builtin_amdgcn_mfma_f32_16x16x32_bf16(pa1, onesf, lacc, 0, 0, 0);
#pragma unroll
    for (int nt = 0; nt < 4; ++nt) {
      int d = nt * 16 + l15;
      int sw = (d & 7) << 4;
      const char* vr = (const char*)&Vl[cur][0] + d * 128;
      bf16x8 v0 = *(const bf16x8*)(vr + ((l4 * 16) ^ sw));
      bf16x8 v1 = *(const bf16x8*)(vr + ((64 + l4 * 16) ^ sw));
      oacc[nt] = __builtin_amdgcn_mfma_f32_16x16x32_bf16(pa0, v0, oacc[nt], 0, 0, 0);
      oacc[nt] = __builtin_amdgcn_mfma_f32_16x16x32_bf16(pa1, v1, oacc[nt], 0, 0, 0);
    }
    __builtin_amdgcn_s_setprio(0);
  }

  // normalize + store ctx (bf16, [b*2048+q][h*64+d]) — zero shuffles
  u16* cb = ctx + (size_t)(b * 2048 + qt * 64 + wv * 16) * 1024 + h * 64;
#pragma unroll
  for (int i = 0; i < 4; ++i) {
    float iv = 1.f / lacc[i];
    int r = l4 * 4 + i;
#pragma unroll
    for (int nt = 0; nt < 4; ++nt)
      cb[(size_t)r * 1024 + nt * 16 + l15] = f2bf(oacc[nt][i] * iv);
  }
}

// ---------------- launch ----------------
extern "C" void kernel_launch(void* const* d_in, const int* in_sizes, int n_in,
                              void* d_out, int out_size, void* d_ws,
                              size_t ws_size, hipStream_t stream) {
  const float* q  = (const float*)d_in[0];
  const float* k  = (const float*)d_in[1];
  const float* v  = (const float*)d_in[2];
  const float* Wq = (const float*)d_in[3];
  const float* bq = (const float*)d_in[4];
  const float* Wk = (const float*)d_in[5];
  const float* bk = (const float*)d_in[6];
  const float* Wv = (const float*)d_in[7];
  const float* bv = (const float*)d_in[8];
  const float* Wo = (const float*)d_in[9];
  const float* bo = (const float*)d_in[10];

  // workspace layout (40 MiB):
  //   [0,8M):    ctx bf16 [4096][1024] (attn out, gemm_out in)
  //   [24M,32M): Wt = bf16 W^T for q,k,v,o
  //   [32M,40M): VtG = V^T bf16 [1024][4096]
  // d_out (16 MiB) doubles as Qb|Kb bf16 scratch until gemm_out overwrites
  // it with the fp32 output (deterministic each call).
  char* ws = (char*)d_ws;
  u16* ctx = (u16*)ws;
  u16* Wt  = (u16*)(ws + 25165824);
  u16* VtG = (u16*)(ws + 33554432);
  u16* Qb  = (u16*)d_out;
  u16* Kb  = Qb + 4194304;

  const float SC2A = 0.0318793585f;  // log2(e)/sqrt(2048), folded into Q

  prep_k<<<dim3(1024), 256, 0, stream>>>(Wq, Wk, Wv, Wo, Wt);
  gemm_proj<<<dim3(32, 8, 3), 256, 0, stream>>>(q, k, v, Wt, bq, bk, bv,
                                                Qb, Kb, VtG, SC2A);
  attn_k<<<dim3(32, 32), 256, 0, stream>>>(Qb, Kb, VtG, ctx);
  gemm_out<<<dim3(32, 8), 256, 0, stream>>>(ctx, Wt + 3 * 1048576, bo,
                                            (float*)d_out);
}

// Round 19
// 104.959 us; speedup vs baseline: 1.2872x; 1.2872x over previous
//
#include <hip/hip_runtime.h>
#include <stdint.h>

typedef unsigned short u16;
typedef unsigned int u32;
typedef u32 u32x4 __attribute__((ext_vector_type(4)));
typedef __bf16 bf16x8 __attribute__((ext_vector_type(8)));
typedef __bf16 bf16x4 __attribute__((ext_vector_type(4)));
typedef float f32x4 __attribute__((ext_vector_type(4)));

// fp32 -> bf16 round-to-nearest-even
__device__ __forceinline__ u16 f2bf(float f) {
  u32 u = __float_as_uint(f);
  u = (u + 0x7fffu + ((u >> 16) & 1u)) >> 16;
  return (u16)u;
}

// async global->LDS, 16B per lane; lds base must be wave-uniform (HW adds lane*16)
__device__ __forceinline__ void gload16(const void* g, void* l) {
  __builtin_amdgcn_global_load_lds(
      (const __attribute__((address_space(1))) void*)g,
      (__attribute__((address_space(3))) void*)l, 16, 0, 0);
}

// ---------------- merged prep: fp32->bf16 cvt (q,k,v) + W^T cvt ----------
// (R18's fused-cvt GEMM regressed 2x — separate BW-bound pass is cheapest.)
__global__ __launch_bounds__(256) void prep_k(
    const float* __restrict__ q, const float* __restrict__ k,
    const float* __restrict__ v, u16* __restrict__ dst,
    const float* __restrict__ w0, const float* __restrict__ w1,
    const float* __restrict__ w2, const float* __restrict__ w3,
    u16* __restrict__ wt) {
  const int id = blockIdx.x;
  if (id < 6144) {
    const int y = id >> 11;          // 0..2 -> q,k,v
    const int x = id & 2047;
    const float* s = (y == 0) ? q : (y == 1) ? k : v;
    u16* d = dst + (size_t)y * 4194304u;
    int e = (x * 256 + threadIdx.x) * 8;
    float4 a = *(const float4*)(s + e);
    float4 b = *(const float4*)(s + e + 4);
    uint4 o;
    o.x = (u32)f2bf(a.x) | ((u32)f2bf(a.y) << 16);
    o.y = (u32)f2bf(a.z) | ((u32)f2bf(a.w) << 16);
    o.z = (u32)f2bf(b.x) | ((u32)f2bf(b.y) << 16);
    o.w = (u32)f2bf(b.z) | ((u32)f2bf(b.w) << 16);
    *(uint4*)(d + e) = o;
    return;
  }
  __shared__ float tile[64][65];
  const int t = id - 6144;
  const int z = t >> 8;            // 0..3 -> Wq,Wk,Wv,Wo
  const int rem = t & 255;
  const int x0 = (rem & 15) * 64, y0 = (rem >> 4) * 64;
  const float* W = (z == 0) ? w0 : (z == 1) ? w1 : (z == 2) ? w2 : w3;
  u16* Wt = wt + (size_t)z * 1048576u;
  const int tx = threadIdx.x & 63, ty = threadIdx.x >> 6;  // 64 x 4
#pragma unroll
  for (int j = 0; j < 16; ++j)
    tile[ty + j * 4][tx] = W[(size_t)(y0 + ty + j * 4) * 1024 + x0 + tx];
  __syncthreads();
#pragma unroll
  for (int j = 0; j < 16; ++j)
    Wt[(size_t)(x0 + ty + j * 4) * 1024 + y0 + tx] = f2bf(tile[tx][ty + j * 4]);
}

// ---------------- merged projection GEMM (Q, K, V^T) ----------------
__global__ __launch_bounds__(256, 3) void gemm_proj(
    const u16* __restrict__ Xb, const u16* __restrict__ Wt,
    const float* __restrict__ bqp, const float* __restrict__ bkp,
    const float* __restrict__ bvp,
    u16* __restrict__ Qb, u16* __restrict__ Kb, u16* __restrict__ VtG,
    float qsc) {
  const int z = blockIdx.z;
  const u16 *A, *Bt;
  const float* bias;
  u16* C;
  int N, bm, bn;
  float osc = 1.f;
  bool rowb = false;
  if (z < 2) {
    A = Xb + (size_t)z * 4194304u;
    Bt = Wt + (size_t)z * 1048576u;
    bias = z ? bkp : bqp;
    C = z ? Kb : Qb;
    N = 1024;
    bm = blockIdx.x * 128;
    bn = blockIdx.y * 128;
    if (z == 0) osc = qsc;
  } else {
    A = Wt + 2u * 1048576u;
    Bt = Xb + 2u * 4194304u;
    bias = bvp;
    C = VtG;
    N = 4096;
    bm = blockIdx.y * 128;
    bn = blockIdx.x * 128;
    rowb = true;
  }

  __shared__ __align__(16) u16 ldsA[128 * 64];
  __shared__ __align__(16) u16 ldsB[128 * 64];

  const int tid = threadIdx.x;
  const int lane = tid & 63, wv = tid >> 6;
  const int wr = wv >> 1, wc = wv & 1;
  const int l15 = lane & 15, l4 = lane >> 4;

  const f32x4 zero4 = {0.f, 0.f, 0.f, 0.f};
  f32x4 acc[4][4];
#pragma unroll
  for (int i = 0; i < 4; ++i)
#pragma unroll
    for (int j = 0; j < 4; ++j) acc[i][j] = zero4;

  for (int kt = 0; kt < 16; ++kt) {
    __syncthreads();
#pragma unroll
    for (int g = 0; g < 4; ++g) {
      int p = g * 256 + tid;
      int row = p >> 3;
      int ss = (p & 7) ^ (row & 7);
      gload16(A + (size_t)(bm + row) * 1024 + kt * 64 + ss * 8,
              (char*)ldsA + (g * 256 + wv * 64) * 16);
    }
#pragma unroll
    for (int g = 0; g < 4; ++g) {
      int p = g * 256 + tid;
      int row = p >> 3;
      int ss = (p & 7) ^ (row & 7);
      gload16(Bt + (size_t)(bn + row) * 1024 + kt * 64 + ss * 8,
              (char*)ldsB + (g * 256 + wv * 64) * 16);
    }
    __syncthreads();

    bf16x8 af[4][2], bfr[4][2];
#pragma unroll
    for (int mf = 0; mf < 4; ++mf) {
      int row = wr * 64 + mf * 16 + l15;
#pragma unroll
      for (int ks = 0; ks < 2; ++ks) {
        int byt = row * 128 + ((ks * 64 + l4 * 16) ^ ((row & 7) << 4));
        af[mf][ks] = *(const bf16x8*)((const char*)ldsA + byt);
      }
    }
#pragma unroll
    for (int nf = 0; nf < 4; ++nf) {
      int row = wc * 64 + nf * 16 + l15;
#pragma unroll
      for (int ks = 0; ks < 2; ++ks) {
        int byt = row * 128 + ((ks * 64 + l4 * 16) ^ ((row & 7) << 4));
        bfr[nf][ks] = *(const bf16x8*)((const char*)ldsB + byt);
      }
    }
#pragma unroll
    for (int mf = 0; mf < 4; ++mf)
#pragma unroll
      for (int nf = 0; nf < 4; ++nf) {
        acc[mf][nf] = __builtin_amdgcn_mfma_f32_16x16x32_bf16(
            af[mf][0], bfr[nf][0], acc[mf][nf], 0, 0, 0);
        acc[mf][nf] = __builtin_amdgcn_mfma_f32_16x16x32_bf16(
            af[mf][1], bfr[nf][1], acc[mf][nf], 0, 0, 0);
      }
  }

  float bcol[4];
  if (!rowb) {
#pragma unroll
    for (int nf = 0; nf < 4; ++nf)
      bcol[nf] = bias[bn + wc * 64 + nf * 16 + l15];
  }
#pragma unroll
  for (int mf = 0; mf < 4; ++mf) {
#pragma unroll
    for (int i = 0; i < 4; ++i) {
      int r = bm + wr * 64 + mf * 16 + l4 * 4 + i;
      float br = rowb ? bias[r] : 0.f;
#pragma unroll
      for (int nf = 0; nf < 4; ++nf) {
        int c = bn + wc * 64 + nf * 16 + l15;
        float val = (acc[mf][nf][i] + (rowb ? br : bcol[nf])) * osc;
        C[(size_t)r * N + c] = f2bf(val);
      }
    }
  }
}

// ---------------- final GEMM: out = ctx @ Wo^T' + bo (fp32) ----------------
__global__ __launch_bounds__(256, 3) void gemm_out(
    const u16* __restrict__ A, const u16* __restrict__ Bt,
    const float* __restrict__ bias, float* __restrict__ C) {
  __shared__ __align__(16) u16 ldsA[128 * 64];
  __shared__ __align__(16) u16 ldsB[128 * 64];

  const int tid = threadIdx.x;
  const int lane = tid & 63, wv = tid >> 6;
  const int wr = wv >> 1, wc = wv & 1;
  const int l15 = lane & 15, l4 = lane >> 4;
  const int bm = blockIdx.x * 128, bn = blockIdx.y * 128;

  const f32x4 zero4 = {0.f, 0.f, 0.f, 0.f};
  f32x4 acc[4][4];
#pragma unroll
  for (int i = 0; i < 4; ++i)
#pragma unroll
    for (int j = 0; j < 4; ++j) acc[i][j] = zero4;

  for (int kt = 0; kt < 16; ++kt) {
    __syncthreads();
#pragma unroll
    for (int g = 0; g < 4; ++g) {
      int p = g * 256 + tid;
      int row = p >> 3;
      int ss = (p & 7) ^ (row & 7);
      gload16(A + (size_t)(bm + row) * 1024 + kt * 64 + ss * 8,
              (char*)ldsA + (g * 256 + wv * 64) * 16);
    }
#pragma unroll
    for (int g = 0; g < 4; ++g) {
      int p = g * 256 + tid;
      int row = p >> 3;
      int ss = (p & 7) ^ (row & 7);
      gload16(Bt + (size_t)(bn + row) * 1024 + kt * 64 + ss * 8,
              (char*)ldsB + (g * 256 + wv * 64) * 16);
    }
    __syncthreads();

    bf16x8 af[4][2], bfr[4][2];
#pragma unroll
    for (int mf = 0; mf < 4; ++mf) {
      int row = wr * 64 + mf * 16 + l15;
#pragma unroll
      for (int ks = 0; ks < 2; ++ks) {
        int byt = row * 128 + ((ks * 64 + l4 * 16) ^ ((row & 7) << 4));
        af[mf][ks] = *(const bf16x8*)((const char*)ldsA + byt);
      }
    }
#pragma unroll
    for (int nf = 0; nf < 4; ++nf) {
      int row = wc * 64 + nf * 16 + l15;
#pragma unroll
      for (int ks = 0; ks < 2; ++ks) {
        int byt = row * 128 + ((ks * 64 + l4 * 16) ^ ((row & 7) << 4));
        bfr[nf][ks] = *(const bf16x8*)((const char*)ldsB + byt);
      }
    }
#pragma unroll
    for (int mf = 0; mf < 4; ++mf)
#pragma unroll
      for (int nf = 0; nf < 4; ++nf) {
        acc[mf][nf] = __builtin_amdgcn_mfma_f32_16x16x32_bf16(
            af[mf][0], bfr[nf][0], acc[mf][nf], 0, 0, 0);
        acc[mf][nf] = __builtin_amdgcn_mfma_f32_16x16x32_bf16(
            af[mf][1], bfr[nf][1], acc[mf][nf], 0, 0, 0);
      }
  }

  float bcol[4];
#pragma unroll
  for (int nf = 0; nf < 4; ++nf)
    bcol[nf] = bias[bn + wc * 64 + nf * 16 + l15];
#pragma unroll
  for (int mf = 0; mf < 4; ++mf) {
#pragma unroll
    for (int i = 0; i < 4; ++i) {
      int r = bm + wr * 64 + mf * 16 + l4 * 4 + i;
#pragma unroll
      for (int nf = 0; nf < 4; ++nf) {
        int c = bn + wc * 64 + nf * 16 + l15;
        C[(size_t)r * 1024 + c] = acc[mf][nf][i] + bcol[nf];
      }
    }
  }
}

// ---------------- causal flash attention: lane-local P + snake balance -----
// R17 body (proven 39.5us, zero bank conflicts) with snake-ordered task
// assignment: per XCD, dispatch round r in {0..3} covers qt-index block
// r*8..r*8+7, ascending on odd rounds, so every CU slot accumulates exactly
// (31-g)+(16+g)+(15-g)+g = 62 iterations — removes the measured 76-vs-48
// makespan imbalance (occupancy decay 26.7%).
__global__ __launch_bounds__(256, 4) void attn_k(
    const u16* __restrict__ Q, const u16* __restrict__ Kb,
    const u16* __restrict__ Vt, u16* __restrict__ ctx) {
  const int id = blockIdx.x + (blockIdx.y << 5);
  const int xcd = id & 7;
  const int kk = id >> 3;               // 0..127
  const int bh = xcd * 4 + (kk & 3);    // 4 bh columns per XCD
  const int r = kk >> 5;                // dispatch round 0..3
  const int g = (kk >> 2) & 7;          // slot within round
  const int qi = r * 8 + ((r & 1) ? (7 - g) : g);
  const int qt = 31 - qi;               // snake: per-slot work sums to 62
  const int b = bh >> 4, h = bh & 15;
  const int tid = threadIdx.x;
  const int lane = tid & 63, wv = tid >> 6;
  const int l15 = lane & 15, l4 = lane >> 4;

  __shared__ __align__(16) u16 Kt[2][64 * 64];   // [kv][d], perm-key swizzled
  __shared__ __align__(16) u16 Vl[2][64 * 64];   // [d][kv], row&7 swizzled

  const u16* KB = Kb + (size_t)(b * 2048) * 1024 + h * 64;
  const u16* VB = Vt + (size_t)(h * 64) * 4096 + b * 2048;

  const u16* qp =
      Q + (size_t)(b * 2048 + qt * 64 + wv * 16 + l15) * 1024 + h * 64;
  bf16x8 qf0 = *(const bf16x8*)(qp + l4 * 8);
  bf16x8 qf1 = *(const bf16x8*)(qp + 32 + l4 * 8);

  const f32x4 zero4 = {0.f, 0.f, 0.f, 0.f};
  f32x4 oacc[4];  // [nt]: O[q=l4*4+i][d=nt*16+l15]
#pragma unroll
  for (int i = 0; i < 4; ++i) oacc[i] = zero4;
  f32x4 lacc = zero4;  // lacc[i] = sum_kv P[q=l4*4+i][kv] (MFMA-accumulated)

  const u32x4 onesw = {0x3F803F80u, 0x3F803F80u, 0x3F803F80u, 0x3F803F80u};
  const bf16x8 onesf = __builtin_bit_cast(bf16x8, onesw);

  auto issueKV = [&](int jt, int bufi) {
    const u16* kb = KB + (size_t)(jt * 64) * 1024;
#pragma unroll
    for (int gg = 0; gg < 2; ++gg) {
      int p = gg * 256 + tid;
      int row = p >> 3;
      int key = (row & 3) | (((row >> 3) & 1) << 2);
      int ss = (p & 7) ^ key;
      gload16(kb + (size_t)row * 1024 + ss * 8,
              (char*)(&Kt[bufi][0]) + (gg * 256 + wv * 64) * 16);
    }
#pragma unroll
    for (int gg = 0; gg < 2; ++gg) {
      int p = gg * 256 + tid;
      int d = p >> 3;
      int ss = (p & 7) ^ (d & 7);
      gload16(VB + (size_t)d * 4096 + jt * 64 + ss * 8,
              (char*)(&Vl[bufi][0]) + (gg * 256 + wv * 64) * 16);
    }
  };

  issueKV(0, 0);
  for (int j = 0; j <= qt; ++j) {
    const int cur = j & 1;
    __syncthreads();  // own-vmcnt drain -> tile j in LDS; frees other buffer
    if (j < qt) issueKV(j + 1, cur ^ 1);

    // S^T tiles with permuted K rows: tile nt reads row =
    // 32*(nt>>1) + 4*(nt&1) + 8*(l15>>2) + (l15&3)
    f32x4 p4[4];
    __builtin_amdgcn_s_setprio(1);
#pragma unroll
    for (int nt = 0; nt < 4; ++nt) {
      int row = ((nt & 2) << 4) + ((nt & 1) << 2) + 8 * (l15 >> 2) + (l15 & 3);
      int key = (row & 3) | (((row >> 3) & 1) << 2);
      int sw = key << 4;
      const char* kr = (const char*)&Kt[cur][0] + row * 128;
      bf16x8 k0 = *(const bf16x8*)(kr + ((l4 * 16) ^ sw));
      bf16x8 k1 = *(const bf16x8*)(kr + ((64 + l4 * 16) ^ sw));
      f32x4 s = zero4;
      s = __builtin_amdgcn_mfma_f32_16x16x32_bf16(k0, qf0, s, 0, 0, 0);
      s = __builtin_amdgcn_mfma_f32_16x16x32_bf16(k1, qf1, s, 0, 0, 0);
      p4[nt] = s;
    }
    __builtin_amdgcn_s_setprio(0);

    if (j == qt) {  // causal mask: kv_local = 32*(nt>>1)+4*(nt&1)+8*l4+i
#pragma unroll
      for (int nt = 0; nt < 4; ++nt) {
        int kvb = ((nt & 2) << 4) + ((nt & 1) << 2) + 8 * l4;
#pragma unroll
        for (int i = 0; i < 4; ++i)
          if (kvb + i > wv * 16 + l15) p4[nt][i] = -1e30f;
      }
    }

    // p = exp2(S) (fixed reference; exp2(-1e30)=0 keeps masking exact)
#pragma unroll
    for (int nt = 0; nt < 4; ++nt)
#pragma unroll
      for (int i = 0; i < 4; ++i) p4[nt][i] = exp2f(p4[nt][i]);

    // PV A-frags directly from registers (k-order matches V's B-frag)
    bf16x4 c0 = __builtin_convertvector(p4[0], bf16x4);
    bf16x4 c1 = __builtin_convertvector(p4[1], bf16x4);
    bf16x4 c2 = __builtin_convertvector(p4[2], bf16x4);
    bf16x4 c3 = __builtin_convertvector(p4[3], bf16x4);
    bf16x8 pa0 = __builtin_shufflevector(c0, c1, 0, 1, 2, 3, 4, 5, 6, 7);
    bf16x8 pa1 = __builtin_shufflevector(c2, c3, 0, 1, 2, 3, 4, 5, 6, 7);

    // O += P V ; lsum += P . ones (on the matrix pipe)
    __builtin_amdgcn_s_setprio(1);
    lacc = __builtin_amdgcn_mfma_f32_16x16x32_bf16(pa0, onesf, lacc, 0, 0, 0);
    lacc = __builtin_amdgcn_mfma_f32_16x16x32_bf16(pa1, onesf, lacc, 0, 0, 0);
#pragma unroll
    for (int nt = 0; nt < 4; ++nt) {
      int d = nt * 16 + l15;
      int sw = (d & 7) << 4;
      const char* vr = (const char*)&Vl[cur][0] + d * 128;
      bf16x8 v0 = *(const bf16x8*)(vr + ((l4 * 16) ^ sw));
      bf16x8 v1 = *(const bf16x8*)(vr + ((64 + l4 * 16) ^ sw));
      oacc[nt] = __builtin_amdgcn_mfma_f32_16x16x32_bf16(pa0, v0, oacc[nt], 0, 0, 0);
      oacc[nt] = __builtin_amdgcn_mfma_f32_16x16x32_bf16(pa1, v1, oacc[nt], 0, 0, 0);
    }
    __builtin_amdgcn_s_setprio(0);
  }

  // normalize + store ctx (bf16, [b*2048+q][h*64+d]) — zero shuffles
  u16* cb = ctx + (size_t)(b * 2048 + qt * 64 + wv * 16) * 1024 + h * 64;
#pragma unroll
  for (int i = 0; i < 4; ++i) {
    float iv = 1.f / lacc[i];
    int rr = l4 * 4 + i;
#pragma unroll
    for (int nt = 0; nt < 4; ++nt)
      cb[(size_t)rr * 1024 + nt * 16 + l15] = f2bf(oacc[nt][i] * iv);
  }
}

// ---------------- launch ----------------
extern "C" void kernel_launch(void* const* d_in, const int* in_sizes, int n_in,
                              void* d_out, int out_size, void* d_ws,
                              size_t ws_size, hipStream_t stream) {
  const float* q  = (const float*)d_in[0];
  const float* k  = (const float*)d_in[1];
  const float* v  = (const float*)d_in[2];
  const float* Wq = (const float*)d_in[3];
  const float* bq = (const float*)d_in[4];
  const float* Wk = (const float*)d_in[5];
  const float* bk = (const float*)d_in[6];
  const float* Wv = (const float*)d_in[7];
  const float* bv = (const float*)d_in[8];
  const float* Wo = (const float*)d_in[9];
  const float* bo = (const float*)d_in[10];

  // workspace layout (40 MiB):
  //   [0,24M):   Xb = bf16(query|key|value); first 8 MiB reused later as ctx
  //   [24M,32M): Wt = bf16 W^T for q,k,v,o
  //   [32M,40M): VtG = V^T bf16 [1024][4096]
  // d_out (16 MiB) doubles as Qb|Kb bf16 scratch until the final GEMM
  // fully overwrites it with fp32 output (deterministic each call).
  char* ws = (char*)d_ws;
  u16* Xb  = (u16*)ws;
  u16* Wt  = (u16*)(ws + 25165824);
  u16* VtG = (u16*)(ws + 33554432);
  u16* ctx = Xb;
  u16* Qb  = (u16*)d_out;
  u16* Kb  = Qb + 4194304;

  const float SC2A = 0.0318793585f;  // log2(e)/sqrt(2048), folded into Q

  prep_k<<<dim3(7168), 256, 0, stream>>>(q, k, v, Xb, Wq, Wk, Wv, Wo, Wt);
  gemm_proj<<<dim3(32, 8, 3), 256, 0, stream>>>(Xb, Wt, bq, bk, bv, Qb, Kb,
                                                VtG, SC2A);
  attn_k<<<dim3(32, 32), 256, 0, stream>>>(Qb, Kb, VtG, ctx);
  gemm_out<<<dim3(32, 8), 256, 0, stream>>>(ctx, Wt + 3 * 1048576, bo,
                                            (float*)d_out);
}

// Round 20
// 101.195 us; speedup vs baseline: 1.3351x; 1.0372x over previous
//
#include <hip/hip_runtime.h>
#include <stdint.h>

typedef unsigned short u16;
typedef unsigned int u32;
typedef u32 u32x4 __attribute__((ext_vector_type(4)));
typedef __bf16 bf16x8 __attribute__((ext_vector_type(8)));
typedef __bf16 bf16x4 __attribute__((ext_vector_type(4)));
typedef float f32x4 __attribute__((ext_vector_type(4)));

// fp32 -> bf16 round-to-nearest-even
__device__ __forceinline__ u16 f2bf(float f) {
  u32 u = __float_as_uint(f);
  u = (u + 0x7fffu + ((u >> 16) & 1u)) >> 16;
  return (u16)u;
}

// async global->LDS, 16B per lane; lds base must be wave-uniform (HW adds lane*16)
__device__ __forceinline__ void gload16(const void* g, void* l) {
  __builtin_amdgcn_global_load_lds(
      (const __attribute__((address_space(1))) void*)g,
      (__attribute__((address_space(3))) void*)l, 16, 0, 0);
}

// ---------------- merged prep: fp32->bf16 cvt (q,k,v) + W^T cvt ----------
__global__ __launch_bounds__(256) void prep_k(
    const float* __restrict__ q, const float* __restrict__ k,
    const float* __restrict__ v, u16* __restrict__ dst,
    const float* __restrict__ w0, const float* __restrict__ w1,
    const float* __restrict__ w2, const float* __restrict__ w3,
    u16* __restrict__ wt) {
  const int id = blockIdx.x;
  if (id < 6144) {
    const int y = id >> 11;          // 0..2 -> q,k,v
    const int x = id & 2047;
    const float* s = (y == 0) ? q : (y == 1) ? k : v;
    u16* d = dst + (size_t)y * 4194304u;
    int e = (x * 256 + threadIdx.x) * 8;
    float4 a = *(const float4*)(s + e);
    float4 b = *(const float4*)(s + e + 4);
    uint4 o;
    o.x = (u32)f2bf(a.x) | ((u32)f2bf(a.y) << 16);
    o.y = (u32)f2bf(a.z) | ((u32)f2bf(a.w) << 16);
    o.z = (u32)f2bf(b.x) | ((u32)f2bf(b.y) << 16);
    o.w = (u32)f2bf(b.z) | ((u32)f2bf(b.w) << 16);
    *(uint4*)(d + e) = o;
    return;
  }
  __shared__ float tile[64][65];
  const int t = id - 6144;
  const int z = t >> 8;            // 0..3 -> Wq,Wk,Wv,Wo
  const int rem = t & 255;
  const int x0 = (rem & 15) * 64, y0 = (rem >> 4) * 64;
  const float* W = (z == 0) ? w0 : (z == 1) ? w1 : (z == 2) ? w2 : w3;
  u16* Wt = wt + (size_t)z * 1048576u;
  const int tx = threadIdx.x & 63, ty = threadIdx.x >> 6;  // 64 x 4
#pragma unroll
  for (int j = 0; j < 16; ++j)
    tile[ty + j * 4][tx] = W[(size_t)(y0 + ty + j * 4) * 1024 + x0 + tx];
  __syncthreads();
#pragma unroll
  for (int j = 0; j < 16; ++j)
    Wt[(size_t)(x0 + ty + j * 4) * 1024 + y0 + tx] = f2bf(tile[tx][ty + j * 4]);
}

// ---------------- merged projection GEMM (Q, K, V^T) ----------------
__global__ __launch_bounds__(256, 3) void gemm_proj(
    const u16* __restrict__ Xb, const u16* __restrict__ Wt,
    const float* __restrict__ bqp, const float* __restrict__ bkp,
    const float* __restrict__ bvp,
    u16* __restrict__ Qb, u16* __restrict__ Kb, u16* __restrict__ VtG,
    float qsc) {
  const int z = blockIdx.z;
  const u16 *A, *Bt;
  const float* bias;
  u16* C;
  int N, bm, bn;
  float osc = 1.f;
  bool rowb = false;
  if (z < 2) {
    A = Xb + (size_t)z * 4194304u;
    Bt = Wt + (size_t)z * 1048576u;
    bias = z ? bkp : bqp;
    C = z ? Kb : Qb;
    N = 1024;
    bm = blockIdx.x * 128;
    bn = blockIdx.y * 128;
    if (z == 0) osc = qsc;
  } else {
    A = Wt + 2u * 1048576u;
    Bt = Xb + 2u * 4194304u;
    bias = bvp;
    C = VtG;
    N = 4096;
    bm = blockIdx.y * 128;
    bn = blockIdx.x * 128;
    rowb = true;
  }

  __shared__ __align__(16) u16 ldsA[128 * 64];
  __shared__ __align__(16) u16 ldsB[128 * 64];

  const int tid = threadIdx.x;
  const int lane = tid & 63, wv = tid >> 6;
  const int wr = wv >> 1, wc = wv & 1;
  const int l15 = lane & 15, l4 = lane >> 4;

  const f32x4 zero4 = {0.f, 0.f, 0.f, 0.f};
  f32x4 acc[4][4];
#pragma unroll
  for (int i = 0; i < 4; ++i)
#pragma unroll
    for (int j = 0; j < 4; ++j) acc[i][j] = zero4;

  for (int kt = 0; kt < 16; ++kt) {
    __syncthreads();
#pragma unroll
    for (int g = 0; g < 4; ++g) {
      int p = g * 256 + tid;
      int row = p >> 3;
      int ss = (p & 7) ^ (row & 7);
      gload16(A + (size_t)(bm + row) * 1024 + kt * 64 + ss * 8,
              (char*)ldsA + (g * 256 + wv * 64) * 16);
    }
#pragma unroll
    for (int g = 0; g < 4; ++g) {
      int p = g * 256 + tid;
      int row = p >> 3;
      int ss = (p & 7) ^ (row & 7);
      gload16(Bt + (size_t)(bn + row) * 1024 + kt * 64 + ss * 8,
              (char*)ldsB + (g * 256 + wv * 64) * 16);
    }
    __syncthreads();

    bf16x8 af[4][2], bfr[4][2];
#pragma unroll
    for (int mf = 0; mf < 4; ++mf) {
      int row = wr * 64 + mf * 16 + l15;
#pragma unroll
      for (int ks = 0; ks < 2; ++ks) {
        int byt = row * 128 + ((ks * 64 + l4 * 16) ^ ((row & 7) << 4));
        af[mf][ks] = *(const bf16x8*)((const char*)ldsA + byt);
      }
    }
#pragma unroll
    for (int nf = 0; nf < 4; ++nf) {
      int row = wc * 64 + nf * 16 + l15;
#pragma unroll
      for (int ks = 0; ks < 2; ++ks) {
        int byt = row * 128 + ((ks * 64 + l4 * 16) ^ ((row & 7) << 4));
        bfr[nf][ks] = *(const bf16x8*)((const char*)ldsB + byt);
      }
    }
#pragma unroll
    for (int mf = 0; mf < 4; ++mf)
#pragma unroll
      for (int nf = 0; nf < 4; ++nf) {
        acc[mf][nf] = __builtin_amdgcn_mfma_f32_16x16x32_bf16(
            af[mf][0], bfr[nf][0], acc[mf][nf], 0, 0, 0);
        acc[mf][nf] = __builtin_amdgcn_mfma_f32_16x16x32_bf16(
            af[mf][1], bfr[nf][1], acc[mf][nf], 0, 0, 0);
      }
  }

  float bcol[4];
  if (!rowb) {
#pragma unroll
    for (int nf = 0; nf < 4; ++nf)
      bcol[nf] = bias[bn + wc * 64 + nf * 16 + l15];
  }
#pragma unroll
  for (int mf = 0; mf < 4; ++mf) {
#pragma unroll
    for (int i = 0; i < 4; ++i) {
      int r = bm + wr * 64 + mf * 16 + l4 * 4 + i;
      float br = rowb ? bias[r] : 0.f;
#pragma unroll
      for (int nf = 0; nf < 4; ++nf) {
        int c = bn + wc * 64 + nf * 16 + l15;
        float val = (acc[mf][nf][i] + (rowb ? br : bcol[nf])) * osc;
        C[(size_t)r * N + c] = f2bf(val);
      }
    }
  }
}

// ---------------- final GEMM: out = ctx @ Wo^T' + bo (fp32) ----------------
// 128x64 tiles -> grid (32,16) = 512 blocks = 2 blocks/CU (the old 128x128
// grid was 256 = exactly 1/CU: no cross-block overlap to hide the barrier
// drain — the mechanism m114 shows the two-barrier loop depends on).
__global__ __launch_bounds__(256, 3) void gemm_out(
    const u16* __restrict__ A, const u16* __restrict__ Bt,
    const float* __restrict__ bias, float* __restrict__ C) {
  __shared__ __align__(16) u16 ldsA[128 * 64];
  __shared__ __align__(16) u16 ldsB[64 * 64];

  const int tid = threadIdx.x;
  const int lane = tid & 63, wv = tid >> 6;
  const int wr = wv >> 1, wc = wv & 1;   // 2x2 waves: 64-row x 32-col each
  const int l15 = lane & 15, l4 = lane >> 4;
  const int bm = blockIdx.x * 128, bn = blockIdx.y * 64;

  const f32x4 zero4 = {0.f, 0.f, 0.f, 0.f};
  f32x4 acc[4][2];
#pragma unroll
  for (int i = 0; i < 4; ++i)
#pragma unroll
    for (int j = 0; j < 2; ++j) acc[i][j] = zero4;

  for (int kt = 0; kt < 16; ++kt) {
    __syncthreads();
#pragma unroll
    for (int g = 0; g < 4; ++g) {
      int p = g * 256 + tid;
      int row = p >> 3;
      int ss = (p & 7) ^ (row & 7);
      gload16(A + (size_t)(bm + row) * 1024 + kt * 64 + ss * 8,
              (char*)ldsA + (g * 256 + wv * 64) * 16);
    }
#pragma unroll
    for (int g = 0; g < 2; ++g) {
      int p = g * 256 + tid;
      int row = p >> 3;
      int ss = (p & 7) ^ (row & 7);
      gload16(Bt + (size_t)(bn + row) * 1024 + kt * 64 + ss * 8,
              (char*)ldsB + (g * 256 + wv * 64) * 16);
    }
    __syncthreads();

    bf16x8 af[4][2], bfr[2][2];
#pragma unroll
    for (int mf = 0; mf < 4; ++mf) {
      int row = wr * 64 + mf * 16 + l15;
#pragma unroll
      for (int ks = 0; ks < 2; ++ks) {
        int byt = row * 128 + ((ks * 64 + l4 * 16) ^ ((row & 7) << 4));
        af[mf][ks] = *(const bf16x8*)((const char*)ldsA + byt);
      }
    }
#pragma unroll
    for (int nf = 0; nf < 2; ++nf) {
      int row = wc * 32 + nf * 16 + l15;
#pragma unroll
      for (int ks = 0; ks < 2; ++ks) {
        int byt = row * 128 + ((ks * 64 + l4 * 16) ^ ((row & 7) << 4));
        bfr[nf][ks] = *(const bf16x8*)((const char*)ldsB + byt);
      }
    }
    __builtin_amdgcn_s_setprio(1);
#pragma unroll
    for (int mf = 0; mf < 4; ++mf)
#pragma unroll
      for (int nf = 0; nf < 2; ++nf) {
        acc[mf][nf] = __builtin_amdgcn_mfma_f32_16x16x32_bf16(
            af[mf][0], bfr[nf][0], acc[mf][nf], 0, 0, 0);
        acc[mf][nf] = __builtin_amdgcn_mfma_f32_16x16x32_bf16(
            af[mf][1], bfr[nf][1], acc[mf][nf], 0, 0, 0);
      }
    __builtin_amdgcn_s_setprio(0);
  }

  float bcol[2];
#pragma unroll
  for (int nf = 0; nf < 2; ++nf)
    bcol[nf] = bias[bn + wc * 32 + nf * 16 + l15];
#pragma unroll
  for (int mf = 0; mf < 4; ++mf) {
#pragma unroll
    for (int i = 0; i < 4; ++i) {
      int r = bm + wr * 64 + mf * 16 + l4 * 4 + i;
#pragma unroll
      for (int nf = 0; nf < 2; ++nf) {
        int c = bn + wc * 32 + nf * 16 + l15;
        C[(size_t)r * 1024 + c] = acc[mf][nf][i] + bcol[nf];
      }
    }
  }
}

// ---------------- causal flash attention: lane-local P (R17/R19, frozen) ---
__global__ __launch_bounds__(256, 4) void attn_k(
    const u16* __restrict__ Q, const u16* __restrict__ Kb,
    const u16* __restrict__ Vt, u16* __restrict__ ctx) {
  const int id = blockIdx.x + (blockIdx.y << 5);
  const int xcd = id & 7;
  const int kk = id >> 3;               // 0..127
  const int bh = xcd * 4 + (kk & 3);    // 4 bh columns per XCD
  const int r = kk >> 5;                // dispatch round 0..3
  const int g = (kk >> 2) & 7;          // slot within round
  const int qi = r * 8 + ((r & 1) ? (7 - g) : g);
  const int qt = 31 - qi;               // snake-balanced task order
  const int b = bh >> 4, h = bh & 15;
  const int tid = threadIdx.x;
  const int lane = tid & 63, wv = tid >> 6;
  const int l15 = lane & 15, l4 = lane >> 4;

  __shared__ __align__(16) u16 Kt[2][64 * 64];   // [kv][d], perm-key swizzled
  __shared__ __align__(16) u16 Vl[2][64 * 64];   // [d][kv], row&7 swizzled

  const u16* KB = Kb + (size_t)(b * 2048) * 1024 + h * 64;
  const u16* VB = Vt + (size_t)(h * 64) * 4096 + b * 2048;

  const u16* qp =
      Q + (size_t)(b * 2048 + qt * 64 + wv * 16 + l15) * 1024 + h * 64;
  bf16x8 qf0 = *(const bf16x8*)(qp + l4 * 8);
  bf16x8 qf1 = *(const bf16x8*)(qp + 32 + l4 * 8);

  const f32x4 zero4 = {0.f, 0.f, 0.f, 0.f};
  f32x4 oacc[4];  // [nt]: O[q=l4*4+i][d=nt*16+l15]
#pragma unroll
  for (int i = 0; i < 4; ++i) oacc[i] = zero4;
  f32x4 lacc = zero4;  // lacc[i] = sum_kv P[q=l4*4+i][kv] (MFMA-accumulated)

  const u32x4 onesw = {0x3F803F80u, 0x3F803F80u, 0x3F803F80u, 0x3F803F80u};
  const bf16x8 onesf = __builtin_bit_cast(bf16x8, onesw);

  auto issueKV = [&](int jt, int bufi) {
    const u16* kb = KB + (size_t)(jt * 64) * 1024;
#pragma unroll
    for (int gg = 0; gg < 2; ++gg) {
      int p = gg * 256 + tid;
      int row = p >> 3;
      int key = (row & 3) | (((row >> 3) & 1) << 2);
      int ss = (p & 7) ^ key;
      gload16(kb + (size_t)row * 1024 + ss * 8,
              (char*)(&Kt[bufi][0]) + (gg * 256 + wv * 64) * 16);
    }
#pragma unroll
    for (int gg = 0; gg < 2; ++gg) {
      int p = gg * 256 + tid;
      int d = p >> 3;
      int ss = (p & 7) ^ (d & 7);
      gload16(VB + (size_t)d * 4096 + jt * 64 + ss * 8,
              (char*)(&Vl[bufi][0]) + (gg * 256 + wv * 64) * 16);
    }
  };

  issueKV(0, 0);
  for (int j = 0; j <= qt; ++j) {
    const int cur = j & 1;
    __syncthreads();  // own-vmcnt drain -> tile j in LDS; frees other buffer
    if (j < qt) issueKV(j + 1, cur ^ 1);

    // S^T tiles with permuted K rows: tile nt reads row =
    // 32*(nt>>1) + 4*(nt&1) + 8*(l15>>2) + (l15&3)
    f32x4 p4[4];
    __builtin_amdgcn_s_setprio(1);
#pragma unroll
    for (int nt = 0; nt < 4; ++nt) {
      int row = ((nt & 2) << 4) + ((nt & 1) << 2) + 8 * (l15 >> 2) + (l15 & 3);
      int key = (row & 3) | (((row >> 3) & 1) << 2);
      int sw = key << 4;
      const char* kr = (const char*)&Kt[cur][0] + row * 128;
      bf16x8 k0 = *(const bf16x8*)(kr + ((l4 * 16) ^ sw));
      bf16x8 k1 = *(const bf16x8*)(kr + ((64 + l4 * 16) ^ sw));
      f32x4 s = zero4;
      s = __builtin_amdgcn_mfma_f32_16x16x32_bf16(k0, qf0, s, 0, 0, 0);
      s = __builtin_amdgcn_mfma_f32_16x16x32_bf16(k1, qf1, s, 0, 0, 0);
      p4[nt] = s;
    }
    __builtin_amdgcn_s_setprio(0);

    if (j == qt) {  // causal mask: kv_local = 32*(nt>>1)+4*(nt&1)+8*l4+i
#pragma unroll
      for (int nt = 0; nt < 4; ++nt) {
        int kvb = ((nt & 2) << 4) + ((nt & 1) << 2) + 8 * l4;
#pragma unroll
        for (int i = 0; i < 4; ++i)
          if (kvb + i > wv * 16 + l15) p4[nt][i] = -1e30f;
      }
    }

    // p = exp2(S) (fixed reference; exp2(-1e30)=0 keeps masking exact)
#pragma unroll
    for (int nt = 0; nt < 4; ++nt)
#pragma unroll
      for (int i = 0; i < 4; ++i) p4[nt][i] = exp2f(p4[nt][i]);

    // PV A-frags directly from registers (k-order matches V's B-frag)
    bf16x4 c0 = __builtin_convertvector(p4[0], bf16x4);
    bf16x4 c1 = __builtin_convertvector(p4[1], bf16x4);
    bf16x4 c2 = __builtin_convertvector(p4[2], bf16x4);
    bf16x4 c3 = __builtin_convertvector(p4[3], bf16x4);
    bf16x8 pa0 = __builtin_shufflevector(c0, c1, 0, 1, 2, 3, 4, 5, 6, 7);
    bf16x8 pa1 = __builtin_shufflevector(c2, c3, 0, 1, 2, 3, 4, 5, 6, 7);

    // O += P V ; lsum += P . ones (on the matrix pipe)
    __builtin_amdgcn_s_setprio(1);
    lacc = __builtin_amdgcn_mfma_f32_16x16x32_bf16(pa0, onesf, lacc, 0, 0, 0);
    lacc = __builtin_amdgcn_mfma_f32_16x16x32_bf16(pa1, onesf, lacc, 0, 0, 0);
#pragma unroll
    for (int nt = 0; nt < 4; ++nt) {
      int d = nt * 16 + l15;
      int sw = (d & 7) << 4;
      const char* vr = (const char*)&Vl[cur][0] + d * 128;
      bf16x8 v0 = *(const bf16x8*)(vr + ((l4 * 16) ^ sw));
      bf16x8 v1 = *(const bf16x8*)(vr + ((64 + l4 * 16) ^ sw));
      oacc[nt] = __builtin_amdgcn_mfma_f32_16x16x32_bf16(pa0, v0, oacc[nt], 0, 0, 0);
      oacc[nt] = __builtin_amdgcn_mfma_f32_16x16x32_bf16(pa1, v1, oacc[nt], 0, 0, 0);
    }
    __builtin_amdgcn_s_setprio(0);
  }

  // normalize + store ctx (bf16, [b*2048+q][h*64+d]) — zero shuffles
  u16* cb = ctx + (size_t)(b * 2048 + qt * 64 + wv * 16) * 1024 + h * 64;
#pragma unroll
  for (int i = 0; i < 4; ++i) {
    float iv = 1.f / lacc[i];
    int rr = l4 * 4 + i;
#pragma unroll
    for (int nt = 0; nt < 4; ++nt)
      cb[(size_t)rr * 1024 + nt * 16 + l15] = f2bf(oacc[nt][i] * iv);
  }
}

// ---------------- launch ----------------
extern "C" void kernel_launch(void* const* d_in, const int* in_sizes, int n_in,
                              void* d_out, int out_size, void* d_ws,
                              size_t ws_size, hipStream_t stream) {
  const float* q  = (const float*)d_in[0];
  const float* k  = (const float*)d_in[1];
  const float* v  = (const float*)d_in[2];
  const float* Wq = (const float*)d_in[3];
  const float* bq = (const float*)d_in[4];
  const float* Wk = (const float*)d_in[5];
  const float* bk = (const float*)d_in[6];
  const float* Wv = (const float*)d_in[7];
  const float* bv = (const float*)d_in[8];
  const float* Wo = (const float*)d_in[9];
  const float* bo = (const float*)d_in[10];

  // workspace layout (40 MiB):
  //   [0,24M):   Xb = bf16(query|key|value); first 8 MiB reused later as ctx
  //   [24M,32M): Wt = bf16 W^T for q,k,v,o
  //   [32M,40M): VtG = V^T bf16 [1024][4096]
  // d_out (16 MiB) doubles as Qb|Kb bf16 scratch until the final GEMM
  // fully overwrites it with fp32 output (deterministic each call).
  char* ws = (char*)d_ws;
  u16* Xb  = (u16*)ws;
  u16* Wt  = (u16*)(ws + 25165824);
  u16* VtG = (u16*)(ws + 33554432);
  u16* ctx = Xb;
  u16* Qb  = (u16*)d_out;
  u16* Kb  = Qb + 4194304;

  const float SC2A = 0.0318793585f;  // log2(e)/sqrt(2048), folded into Q

  prep_k<<<dim3(7168), 256, 0, stream>>>(q, k, v, Xb, Wq, Wk, Wv, Wo, Wt);
  gemm_proj<<<dim3(32, 8, 3), 256, 0, stream>>>(Xb, Wt, bq, bk, bv, Qb, Kb,
                                                VtG, SC2A);
  attn_k<<<dim3(32, 32), 256, 0, stream>>>(Qb, Kb, VtG, ctx);
  gemm_out<<<dim3(32, 16), 256, 0, stream>>>(ctx, Wt + 3 * 1048576, bo,
                                             (float*)d_out);
}